// Round 5
// baseline (151.438 us; speedup 1.0000x reference)
//
#include <hip/hip_runtime.h>

#define B_ 4
#define C_ 256
#define N_ 4096
#define E_ 32

typedef _Float16 f16x8 __attribute__((ext_vector_type(8)));
typedef _Float16 f16x4 __attribute__((ext_vector_type(4)));
typedef _Float16 f16x2 __attribute__((ext_vector_type(2)));
typedef float f32x4 __attribute__((ext_vector_type(4)));
typedef float f32x2 __attribute__((ext_vector_type(2)));

#define LOG2E 1.44269504088896f

// ---------------------------------------------------------------------------
// Kernel 1: K/Q/V 1x1-conv projections via f16 MFMA. One matrix per block.
//   Kb[b][n][e] = f, Qb[b][n][e] = g * log2(e), Vb[b][e][n] = h.
// ---------------------------------------------------------------------------
__global__ __launch_bounds__(256) void proj_kernel(
    const float* __restrict__ x,
    const float* __restrict__ Wk, const float* __restrict__ bk,
    const float* __restrict__ Wq, const float* __restrict__ bq,
    const float* __restrict__ Wv, const float* __restrict__ bv,
    _Float16* __restrict__ Qb, _Float16* __restrict__ Kb, _Float16* __restrict__ Vb)
{
    const int m   = blockIdx.x >> 8;         // 0=K, 1=Q, 2=V
    const int rem = blockIdx.x & 255;
    const int b   = rem >> 6;
    const int n0  = (rem & 63) << 6;
    const int t    = threadIdx.x;
    const int lane = t & 63;
    const int wave = t >> 6;
    const int l15  = lane & 15;
    const int quad = lane >> 4;

    __shared__ _Float16 xT[64][264];   // x tile transposed: [n_local][c]
    __shared__ _Float16 Wl[32][264];   // this matrix's weights: [e][c]

    const float* W    = (m == 0) ? Wk : (m == 1) ? Wq : Wv;
    const float* bias = (m == 0) ? bk : (m == 1) ? bq : bv;

    for (int i4 = t; i4 < (E_ * C_) / 4; i4 += 256) {
        float4 wv = ((const float4*)W)[i4];
        int e = (i4 * 4) >> 8, c = (i4 * 4) & 255;
        f16x4 tp = {(_Float16)wv.x, (_Float16)wv.y, (_Float16)wv.z, (_Float16)wv.w};
        *(f16x4*)&Wl[e][c] = tp;
    }
    for (int i4 = t; i4 < (64 * 256) / 4; i4 += 256) {
        int j4 = (i4 & 15) * 4;
        int c  = i4 >> 4;
        float4 xv = *(const float4*)(x + (size_t)(b * C_ + c) * N_ + n0 + j4);
        xT[j4 + 0][c] = (_Float16)xv.x;
        xT[j4 + 1][c] = (_Float16)xv.y;
        xT[j4 + 2][c] = (_Float16)xv.z;
        xT[j4 + 3][c] = (_Float16)xv.w;
    }
    __syncthreads();

    f16x8 Bf[8];
    for (int kk = 0; kk < 8; ++kk)
        Bf[kk] = *(const f16x8*)&xT[wave * 16 + l15][kk * 32 + quad * 8];

    const float sc = (m == 1) ? LOG2E : 1.0f;
    for (int et = 0; et < 2; ++et) {
        f32x4 acc = {0.f, 0.f, 0.f, 0.f};
        for (int kk = 0; kk < 8; ++kk) {
            f16x8 Af = *(const f16x8*)&Wl[et * 16 + l15][kk * 32 + quad * 8];
            acc = __builtin_amdgcn_mfma_f32_16x16x32_f16(Af, Bf[kk], acc, 0, 0, 0);
        }
        const int n = n0 + wave * 16 + l15;
        for (int r = 0; r < 4; ++r) {
            const int e = et * 16 + quad * 4 + r;
            float v = (acc[r] + bias[e]) * sc;
            _Float16 hv = (_Float16)v;
            if      (m == 0) Kb[(size_t)(b * N_ + n) * E_ + e] = hv;
            else if (m == 1) Qb[(size_t)(b * N_ + n) * E_ + e] = hv;
            else             Vb[(size_t)(b * E_ + e) * N_ + n] = hv;
        }
    }
}

// ---------------------------------------------------------------------------
// Kernel 2: split-i flash attention, transposed-S form, SOFTWARE-PIPELINED.
// R5 change: the asm lgkmcnt barrier's "memory" clobber was serializing ALL
// loads behind each iteration's softmax -> ~2x L2 latency exposed per it.
// Now: K tile preloaded; per it, V(cur) and K(next) loads are issued AFTER
// the barrier (in source) so they fly under the PV MFMAs / next softmax.
// ---------------------------------------------------------------------------
__global__ __launch_bounds__(256, 4) void attn_kernel(
    const _Float16* __restrict__ Qb, const _Float16* __restrict__ Kb,
    const _Float16* __restrict__ Vb, _Float16* __restrict__ Ob)
{
    const int wave = threadIdx.x >> 6;     // i-split 0..3
    const int lane = threadIdx.x & 63;
    const int l15  = lane & 15, quad = lane >> 4;
    const int jg   = blockIdx.x;           // 0..1023
    const int b    = jg >> 8;
    const int j0   = (jg & 255) << 4;

    __shared__ _Float16 pb[4][16][136];    // per-wave P^T->B-frag buffer
    __shared__ float    osum[4][16][36];   // per-wave scaled O^T for merge
    __shared__ float    mls[4][2][16];     // per-wave (m, l) per j

    // Q B-frag: B[k=e][n=j], lane j=l15, k=quad*8.. from Qb[j][e]
    f16x8 Qf = *(const f16x8*)(Qb + (size_t)(b * N_ + j0 + l15) * E_ + quad * 8);

    f32x4 O0 = {0, 0, 0, 0}, O1 = {0, 0, 0, 0};   // O^T[e][j]
    float mrow = -1e30f, lsum = 0.f;               // per-lane (per-j) state

    const _Float16* Kbase = Kb + (size_t)b * N_ * E_;
    const _Float16* Vbase = Vb + (size_t)b * E_ * N_;
    const int ibase = wave << 10;

    // preload K tile 0 (8 x b128, 1 KB contiguous per instr)
    f16x8 Kf[8];
    for (int s = 0; s < 8; ++s)
        Kf[s] = *(const f16x8*)(Kbase + (size_t)(ibase + s * 16 + l15) * E_ + quad * 8);

    for (int it = 0; it < 8; ++it) {
        const int i0 = ibase + it * 128;
        // S^T tiles: D[i][j], A=K (m=i), B=Q (n=j)
        f32x4 S[8];
        for (int s = 0; s < 8; ++s) {
            f32x4 z = {0, 0, 0, 0};
            S[s] = __builtin_amdgcn_mfma_f32_16x16x32_f16(Kf[s], Qf, z, 0, 0, 0);
        }
        // softmax over i: 32 in-lane regs + 2 shfls across quads
        float mx = -1e30f;
        for (int s = 0; s < 8; ++s)
            for (int r = 0; r < 4; ++r) mx = fmaxf(mx, S[s][r]);
        mx = fmaxf(mx, __shfl_xor(mx, 16));
        mx = fmaxf(mx, __shfl_xor(mx, 32));
        float mnew  = fmaxf(mrow, mx);
        float alpha = exp2f(mrow - mnew);          // log2 domain
        mrow = mnew;
        float ps = 0.f;
        for (int s = 0; s < 8; ++s)
            for (int r = 0; r < 4; ++r) {
                float p = exp2f(S[s][r] - mnew);
                S[s][r] = p;
                ps += p;
            }
        lsum = lsum * alpha + ps;
        for (int r = 0; r < 4; ++r) { O0[r] *= alpha; O1[r] *= alpha; }
        // P^T (D-layout) -> B-frag layout: packed b64 writes
        for (int s = 0; s < 8; ++s) {
            f16x4 tp = {(_Float16)S[s][0], (_Float16)S[s][1],
                        (_Float16)S[s][2], (_Float16)S[s][3]};
            *(f16x4*)&pb[wave][l15][s * 16 + quad * 4] = tp;
        }
        asm volatile("s_waitcnt lgkmcnt(0)" ::: "memory");  // wave-local order
        f16x8 P[4];
        for (int kc = 0; kc < 4; ++kc)
            P[kc] = *(const f16x8*)&pb[wave][l15][kc * 32 + quad * 8];
        // issue V(cur) then K(next) loads — after the clobber, before PV use
        f16x8 Va[4], Vc[4];
        for (int kc = 0; kc < 4; ++kc) {
            Va[kc] = *(const f16x8*)(Vbase + (size_t)l15 * N_ + i0 + kc * 32 + quad * 8);
            Vc[kc] = *(const f16x8*)(Vbase + (size_t)(16 + l15) * N_ + i0 + kc * 32 + quad * 8);
        }
        const int inext = (it < 7) ? (i0 + 128) : ibase;   // clamp (dummy last)
        for (int s = 0; s < 8; ++s)
            Kf[s] = *(const f16x8*)(Kbase + (size_t)(inext + s * 16 + l15) * E_ + quad * 8);
        // PV: O^T += V x P
        for (int kc = 0; kc < 4; ++kc) {
            O0 = __builtin_amdgcn_mfma_f32_16x16x32_f16(Va[kc], P[kc], O0, 0, 0, 0);
            O1 = __builtin_amdgcn_mfma_f32_16x16x32_f16(Vc[kc], P[kc], O1, 0, 0, 0);
        }
    }

    // finish per-split l (sum over quads), publish (m, l)
    lsum += __shfl_xor(lsum, 16);
    lsum += __shfl_xor(lsum, 32);
    if (quad == 0) { mls[wave][0][l15] = mrow; mls[wave][1][l15] = lsum; }
    __syncthreads();

    // log-sum-exp combine weights (redundant per quad, all in regs)
    float M = -1e30f, ms[4], ls[4];
    for (int s = 0; s < 4; ++s) {
        ms[s] = mls[s][0][l15]; ls[s] = mls[s][1][l15];
        M = fmaxf(M, ms[s]);
    }
    float L = 0.f;
    for (int s = 0; s < 4; ++s) L += ls[s] * exp2f(ms[s] - M);
    const float w = exp2f(mrow - M) / L;

    *(f32x4*)&osum[wave][l15][quad * 4]      = O0 * w;
    *(f32x4*)&osum[wave][l15][16 + quad * 4] = O1 * w;
    __syncthreads();

    // final cross-split sum; coalesced f16x2 stores to Ob[n][e]
    const int j  = threadIdx.x >> 4;
    const int e2 = (threadIdx.x & 15) * 2;
    float a0 = 0.f, a1 = 0.f;
    for (int s = 0; s < 4; ++s) {
        f32x2 v = *(const f32x2*)&osum[s][j][e2];
        a0 += v[0]; a1 += v[1];
    }
    f16x2 o2 = {(_Float16)a0, (_Float16)a1};
    *(f16x2*)(Ob + (size_t)(b * N_ + j0 + j) * E_ + e2) = o2;
}

// ---------------------------------------------------------------------------
// Kernel 3: output projection + bias + residual, c-split (1024 blocks, 4/CU).
// ---------------------------------------------------------------------------
__global__ __launch_bounds__(256) void out_kernel(
    const _Float16* __restrict__ Ob, const float* __restrict__ Wo,
    const float* __restrict__ bo, const float* __restrict__ x,
    float* __restrict__ out)
{
    const int bi  = blockIdx.x;            // 0..1023
    const int b   = bi >> 8;
    const int rem = bi & 255;
    const int n0  = (rem >> 2) << 6;       // n tile of 64
    const int cq  = rem & 3;               // c quarter (64 channels)
    const int t = threadIdx.x, lane = t & 63, wave = t >> 6;
    const int l15 = lane & 15, quad = lane >> 4;

    __shared__ _Float16 Wl[64][40];        // [c_local][e]
    for (int i4 = t; i4 < (64 * E_) / 4; i4 += 256) {
        int c = (i4 * 4) >> 5, e = (i4 * 4) & 31;
        float4 wv = *(const float4*)(Wo + (size_t)(cq * 64 + c) * E_ + e);
        f16x4 tp = {(_Float16)wv.x, (_Float16)wv.y, (_Float16)wv.z, (_Float16)wv.w};
        *(f16x4*)&Wl[c][e] = tp;
    }
    __syncthreads();

    const int nloc = wave * 16 + l15;
    f16x8 Bf = *(const f16x8*)(Ob + (size_t)(b * N_ + n0 + nloc) * E_ + quad * 8);

    float* out_y = out;
    float* out_o = out + (size_t)B_ * C_ * N_;

    for (int tt = 0; tt < 4; ++tt) {
        f16x8 Af = *(const f16x8*)&Wl[tt * 16 + l15][quad * 8];
        f32x4 z = {0, 0, 0, 0};
        f32x4 acc = __builtin_amdgcn_mfma_f32_16x16x32_f16(Af, Bf, z, 0, 0, 0);
        for (int r = 0; r < 4; ++r) {
            const int c = cq * 64 + tt * 16 + quad * 4 + r;
            size_t idx = (size_t)(b * C_ + c) * N_ + n0 + nloc;
            float ov = acc[r] + bo[c];
            out_o[idx] = ov;
            out_y[idx] = 0.5f * ov + x[idx];
        }
    }
    if (bi == 0 && t == 0)
        out[(size_t)2 * B_ * C_ * N_] = 0.5f;   // gamma (non-learned)
}

// ---------------------------------------------------------------------------
extern "C" void kernel_launch(void* const* d_in, const int* in_sizes, int n_in,
                              void* d_out, int out_size, void* d_ws, size_t ws_size,
                              hipStream_t stream)
{
    const float* x  = (const float*)d_in[0];
    const float* Wk = (const float*)d_in[1];
    const float* bk = (const float*)d_in[2];
    const float* Wq = (const float*)d_in[3];
    const float* bq = (const float*)d_in[4];
    const float* Wv = (const float*)d_in[5];
    const float* bv = (const float*)d_in[6];
    const float* Wo = (const float*)d_in[7];
    const float* bo = (const float*)d_in[8];
    float* out = (float*)d_out;

    char* ws = (char*)d_ws;
    _Float16* Qb = (_Float16*)(ws);                   // 1 MB [B][N][E]
    _Float16* Kb = (_Float16*)(ws + (1u << 20));      // 1 MB [B][N][E]
    _Float16* Vb = (_Float16*)(ws + (2u << 20));      // 1 MB [B][E][N]
    _Float16* Ob = (_Float16*)(ws + (3u << 20));      // 1 MB [B][N][E]

    proj_kernel<<<dim3(3 * B_ * (N_ / 64)), dim3(256), 0, stream>>>(
        x, Wk, bk, Wq, bq, Wv, bv, Qb, Kb, Vb);
    attn_kernel<<<dim3(B_ * (N_ / 16)), dim3(256), 0, stream>>>(
        Qb, Kb, Vb, Ob);
    out_kernel <<<dim3(4 * B_ * (N_ / 64)), dim3(256), 0, stream>>>(
        Ob, Wo, bo, x, out);
}